// Round 3
// baseline (437.104 us; speedup 1.0000x reference)
//
#include <hip/hip_runtime.h>

typedef unsigned int uint32;
typedef unsigned short u16;
typedef __attribute__((ext_vector_type(8))) short short8;
typedef __attribute__((ext_vector_type(4))) float f32x4;

#define NG 1024

__device__ __forceinline__ u16 f2bf(float f) {
  uint32 u = __builtin_bit_cast(uint32, f);
  u += 0x7fffu + ((u >> 16) & 1u);   // round-to-nearest-even
  return (u16)(u >> 16);
}

// async global->LDS DMA, 16B per lane; LDS dest must be wave-uniform base (HW adds lane*16)
__device__ __forceinline__ void glds16(const void* g, void* l) {
  __builtin_amdgcn_global_load_lds((const __attribute__((address_space(1))) void*)g,
                                   (__attribute__((address_space(3))) void*)l,
                                   16, 0, 0);
}

// ---- manual grid barrier (all 256 blocks co-resident: 1 block/CU).
// arrive at cnt[0], release generation at cnt[16] (separate lines).
// AGENT-scope atomics + threadfence = cross-XCD L2 writeback/invalidate. ----
__device__ __forceinline__ void gbar(uint32* cnt, uint32 nb) {
  __syncthreads();
  if (threadIdx.x == 0) {
    uint32* arrive = cnt;
    uint32* release = cnt + 16;
    __threadfence();   // release: make this block's writes visible device-wide
    uint32 gen = __hip_atomic_load(release, __ATOMIC_RELAXED, __HIP_MEMORY_SCOPE_AGENT);
    uint32 old = __hip_atomic_fetch_add(arrive, 1u, __ATOMIC_ACQ_REL, __HIP_MEMORY_SCOPE_AGENT);
    if (old == nb - 1u) {
      __hip_atomic_store(arrive, 0u, __ATOMIC_RELAXED, __HIP_MEMORY_SCOPE_AGENT);
      __hip_atomic_fetch_add(release, 1u, __ATOMIC_ACQ_REL, __HIP_MEMORY_SCOPE_AGENT);
    } else {
      while (__hip_atomic_load(release, __ATOMIC_ACQUIRE, __HIP_MEMORY_SCOPE_AGENT) == gen) {
        __builtin_amdgcn_s_sleep(2);
      }
    }
    __threadfence();   // acquire: invalidate stale cached lines before reading peers' data
  }
  __syncthreads();
}

// swizzled LDS tile read: linear [64][128B] tile, chunk-XOR ((r&7)<<4)
__device__ __forceinline__ short8 ldfrag(const u16* tile, int r, int kkB) {
  const char* p = (const char*)tile + r * 128 + (kkB ^ ((r & 7) << 4));
  return __builtin_bit_cast(short8, *(const uint4*)p);
}

// ---------------- one 64x64 output tile of C = A@B (B passed TRANSPOSED as BT[n][k]).
// depth-2 global_load_lds pipeline (3-buffer ring), counted vmcnt, raw barriers. ----
__device__ __forceinline__ void mm_tile(const u16* __restrict__ A,
                                        const u16* __restrict__ BT,
                                        u16* C, u16* CT, u16* CTI,
                                        int bid, u16* sA, u16* sB) {
  const int t = threadIdx.x;
  const int bm = (bid & 15) * 64;
  const int bn = (bid >> 4) * 64;
  const int wv = t >> 6;
  const int lane = t & 63;
  const int quad = lane >> 4;
  const int l15 = lane & 15;
  const int m0w = (wv & 3) * 16;   // 16-row strip per wave
  const int n0w = (wv >> 2) * 32;  // 32-col strip per wave

  // staging: LDS linear (slot t*16B); global source col inverse-swizzled (rule 21)
  const int srow = t >> 3;                 // 0..63
  const int scolb = (t & 7) << 4;          // byte col 0..112
  const int scol = (scolb ^ ((srow & 7) << 4)) >> 1;  // elem col
  const u16* aS = A + (size_t)(bm + srow) * NG + scol;
  const u16* bS = BT + (size_t)(bn + srow) * NG + scol;
  const int ldoff = wv << 9;   // per-wave 1KB slice within a buffer

  f32x4 acc[2];
  acc[0] = (f32x4){0.f, 0.f, 0.f, 0.f};
  acc[1] = (f32x4){0.f, 0.f, 0.f, 0.f};

  // prologue: stage kb=0 and kb=1
  glds16(aS, sA + ldoff);
  glds16(bS, sB + ldoff);
  glds16(aS + 64, sA + 4096 + ldoff);
  glds16(bS + 64, sB + 4096 + ldoff);

#pragma unroll
  for (int kb = 0; kb < 16; ++kb) {
    if (kb < 14) {
      const int nb = (kb + 2) % 3;
      glds16(aS + (kb + 2) * 64, sA + nb * 4096 + ldoff);
      glds16(bS + (kb + 2) * 64, sB + nb * 4096 + ldoff);
      asm volatile("s_waitcnt vmcnt(4)" ::: "memory");  // kb landed; kb+1,kb+2 in flight
    } else if (kb == 14) {
      asm volatile("s_waitcnt vmcnt(2)" ::: "memory");
    } else {
      asm volatile("s_waitcnt vmcnt(0)" ::: "memory");
    }
    __builtin_amdgcn_s_barrier();
    __builtin_amdgcn_sched_barrier(0);
    const u16* At = sA + (kb % 3) * 4096;
    const u16* Bt = sB + (kb % 3) * 4096;
#pragma unroll
    for (int ks = 0; ks < 2; ++ks) {
      int kkB = ks * 64 + quad * 16;
      short8 af = ldfrag(At, m0w + l15, kkB);
      short8 b0 = ldfrag(Bt, n0w + l15, kkB);
      short8 b1 = ldfrag(Bt, n0w + 16 + l15, kkB);
      acc[0] = __builtin_amdgcn_mfma_f32_16x16x32_bf16(af, b0, acc[0], 0, 0, 0);
      acc[1] = __builtin_amdgcn_mfma_f32_16x16x32_bf16(af, b1, acc[1], 0, 0, 0);
    }
    __builtin_amdgcn_sched_barrier(0);
    __builtin_amdgcn_s_barrier();   // protect ring buffer about to be re-staged
  }

#pragma unroll
  for (int cb = 0; cb < 2; ++cb) {
    int gcol = bn + n0w + cb * 16 + l15;
    int grow = bm + m0w + quad * 4;
    f32x4 v = acc[cb];
    u16 h[4], hI[4];
#pragma unroll
    for (int rr = 0; rr < 4; ++rr) {
      float f = v[rr];
      h[rr] = f2bf(f);
      hI[rr] = f2bf(f + ((gcol == grow + rr) ? 1.0f : 0.0f));
    }
    if (C) {
#pragma unroll
      for (int rr = 0; rr < 4; ++rr) C[(size_t)(grow + rr) * NG + gcol] = h[rr];
    }
    if (CT) {
      uint2 pk;
      pk.x = (uint32)h[0] | ((uint32)h[1] << 16);
      pk.y = (uint32)h[2] | ((uint32)h[3] << 16);
      *(uint2*)&CT[(size_t)gcol * NG + grow] = pk;
    }
    if (CTI) {
      uint2 pk;
      pk.x = (uint32)hI[0] | ((uint32)hI[1] << 16);
      pk.y = (uint32)hI[2] | ((uint32)hI[3] << 16);
      *(uint2*)&CTI[(size_t)gcol * NG + grow] = pk;
    }
  }
}

// ---------------- fused inverse chain: transpose + 3 mm rounds, manual grid barrier ----
// W = (I - A^T)^{-1} ~= (I+M)(I+M^2)(I+M^4), M = A^T.  Round 3 writes W into Msq's buffer.
__global__ __launch_bounds__(512) void k_inv(const float* __restrict__ A,
                                             u16* __restrict__ M,
                                             u16* __restrict__ MT,
                                             u16* __restrict__ P,
                                             u16* __restrict__ Msq,   // also W output
                                             u16* __restrict__ MsqT,
                                             u16* __restrict__ MsqTI,
                                             u16* __restrict__ M4TI,
                                             u16* __restrict__ B2,
                                             uint32* __restrict__ bar) {
  __shared__ __align__(16) u16 smem[24576];   // 48 KB: sA 3x8KB | sB 3x8KB
  u16* sA = smem;
  u16* sB = smem + 12288;

  const int t = threadIdx.x;
  const int bid = blockIdx.x;

  {  // ---- phase 0: M=bf16(A^T), MT=bf16(A), P=bf16(I+A^T), one 64x64 tile/block ----
    float* tile = (float*)smem;   // [64][65]
    const int i0 = (bid & 15) * 64, j0 = (bid >> 4) * 64;
    const int rl = t >> 3;        // 0..63
    const int c8 = (t & 7) * 8;   // 0..56
    const float* src = A + (size_t)(j0 + rl) * NG + i0 + c8;
    float4 v0 = *(const float4*)src;
    float4 v1 = *(const float4*)(src + 4);
    float* tr = tile + rl * 65 + c8;
    tr[0] = v0.x; tr[1] = v0.y; tr[2] = v0.z; tr[3] = v0.w;
    tr[4] = v1.x; tr[5] = v1.y; tr[6] = v1.z; tr[7] = v1.w;
    uint4 pk;
    pk.x = (uint32)f2bf(v0.x) | ((uint32)f2bf(v0.y) << 16);
    pk.y = (uint32)f2bf(v0.z) | ((uint32)f2bf(v0.w) << 16);
    pk.z = (uint32)f2bf(v1.x) | ((uint32)f2bf(v1.y) << 16);
    pk.w = (uint32)f2bf(v1.z) | ((uint32)f2bf(v1.w) << 16);
    *(uint4*)&MT[(size_t)(j0 + rl) * NG + i0 + c8] = pk;   // MT = (A^T)^T = A
    __syncthreads();
    const int gi = i0 + rl;
    u16 mh[8], ph[8];
#pragma unroll
    for (int u = 0; u < 8; ++u) {
      float f = tile[(c8 + u) * 65 + rl];                  // = M[gi][j0+c8+u]
      mh[u] = f2bf(f);
      ph[u] = f2bf(f + ((gi == (j0 + c8 + u)) ? 1.0f : 0.0f));
    }
    uint4 mk, pp;
    mk.x = (uint32)mh[0] | ((uint32)mh[1] << 16);
    mk.y = (uint32)mh[2] | ((uint32)mh[3] << 16);
    mk.z = (uint32)mh[4] | ((uint32)mh[5] << 16);
    mk.w = (uint32)mh[6] | ((uint32)mh[7] << 16);
    pp.x = (uint32)ph[0] | ((uint32)ph[1] << 16);
    pp.y = (uint32)ph[2] | ((uint32)ph[3] << 16);
    pp.z = (uint32)ph[4] | ((uint32)ph[5] << 16);
    pp.w = (uint32)ph[6] | ((uint32)ph[7] << 16);
    *(uint4*)&M[(size_t)gi * NG + j0 + c8] = mk;
    *(uint4*)&P[(size_t)gi * NG + j0 + c8] = pp;
  }
  gbar(bar, 256);
  // round 1: Msq = M*M, MsqT = Msq^T, MsqTI = I + Msq^T
  mm_tile(M, MT, Msq, MsqT, MsqTI, bid, sA, sB);
  gbar(bar, 256);
  // round 2 (two independent tiles per block): M4TI = (I+M^4)^T ; B2 = (I+M)(I+M^2)
  mm_tile(Msq, MsqT, nullptr, nullptr, M4TI, bid, sA, sB);
  mm_tile(P, MsqTI, B2, nullptr, nullptr, bid, sA, sB);
  gbar(bar, 256);
  // round 3: W = B2 * (I+M^4)   (written into Msq's buffer)
  mm_tile(B2, M4TI, Msq, nullptr, nullptr, bid, sA, sB);
}

// sigT: dense [64][128] u16 with chunk-XOR swizzle ((d^(d>>3))&7)<<4 on byte-col.
__device__ __forceinline__ int sigT_byte(int d, int jb) {
  return (d << 8) + (jb ^ (((d ^ (d >> 3)) & 7) << 4));
}

// ---------------- fused: sigma = mu+eps*exp(ls) (+store), gather W[idx,idx], bmm ----
__global__ __launch_bounds__(256) void k_bmm(const u16* __restrict__ W,
                                             const float* __restrict__ mu,
                                             const float* __restrict__ ls,
                                             const float* __restrict__ ep,
                                             const int* __restrict__ nidx,
                                             float* __restrict__ sig,
                                             float* __restrict__ z) {
  __shared__ __align__(16) u16 s_sub[128][136];
  __shared__ __align__(16) u16 s_sigT[8192];
  __shared__ __align__(16) u16 s_row[4][2][1024];   // per-wave double-buffered row
  __shared__ int s_idx[128];

  const int b = blockIdx.x;
  const int t = threadIdx.x;
  const int w = t >> 6;
  const int lane = t & 63;

  if (t < 128) s_idx[t] = nidx[b * 128 + t];

  {  // sigma fused: read mu/ls/ep once, write sig (streaming), stage bf16 sigT
    const size_t off = (size_t)b * 2048;  // float4 units
    const f32x4* mp = (const f32x4*)mu + off;
    const f32x4* lp = (const f32x4*)ls + off;
    const f32x4* epp = (const f32x4*)ep + off;
    f32x4* sp = (f32x4*)sig + off;
#pragma unroll
    for (int q = 0; q < 8; ++q) {
      int f = t + q * 256;
      f32x4 m = __builtin_nontemporal_load(mp + f);
      f32x4 l = __builtin_nontemporal_load(lp + f);
      f32x4 e = __builtin_nontemporal_load(epp + f);
      f32x4 v;
      v.x = m.x + e.x * expf(l.x);
      v.y = m.y + e.y * expf(l.y);
      v.z = m.z + e.z * expf(l.z);
      v.w = m.w + e.w * expf(l.w);
      __builtin_nontemporal_store(v, sp + f);   // sig never re-read (LDS copy feeds MFMA)
      int j = f >> 4;            // k index 0..127
      int d0 = (f & 15) << 2;    // d index 0..63
      *(u16*)((char*)s_sigT + sigT_byte(d0 + 0, j << 1)) = f2bf(v.x);
      *(u16*)((char*)s_sigT + sigT_byte(d0 + 1, j << 1)) = f2bf(v.y);
      *(u16*)((char*)s_sigT + sigT_byte(d0 + 2, j << 1)) = f2bf(v.z);
      *(u16*)((char*)s_sigT + sigT_byte(d0 + 3, j << 1)) = f2bf(v.w);
    }
  }
  __syncthreads();

  {  // W row broadcast via LDS-DMA, then gather columns
    const int gc0 = s_idx[2 * lane];
    const int gc1 = s_idx[2 * lane + 1];
    int r0 = s_idx[w];
    glds16(W + (size_t)r0 * NG + lane * 8, &s_row[w][0][0]);
    glds16(W + (size_t)r0 * NG + 512 + lane * 8, &s_row[w][0][512]);
    for (int it = 0; it < 32; ++it) {
      const int cb = it & 1;
      if (it < 31) {
        int rn = s_idx[w + (it + 1) * 4];
        glds16(W + (size_t)rn * NG + lane * 8, &s_row[w][cb ^ 1][0]);
        glds16(W + (size_t)rn * NG + 512 + lane * 8, &s_row[w][cb ^ 1][512]);
        asm volatile("s_waitcnt vmcnt(2)" ::: "memory");  // current row landed; next in flight
      } else {
        asm volatile("s_waitcnt vmcnt(0)" ::: "memory");
      }
      int i = w + it * 4;
      uint32 lo = s_row[w][cb][gc0];
      uint32 hi = s_row[w][cb][gc1];
      *(uint32*)&s_sub[i][2 * lane] = lo | (hi << 16);  // packed b32, 2-way free
    }
  }
  __syncthreads();

  const int quad = lane >> 4;
  const int l15 = lane & 15;
  f32x4 acc[2][4];
#pragma unroll
  for (int a = 0; a < 2; ++a)
#pragma unroll
    for (int c = 0; c < 4; ++c) acc[a][c] = (f32x4){0.f, 0.f, 0.f, 0.f};

#pragma unroll
  for (int kt = 0; kt < 4; ++kt) {
    int kk = kt * 32 + quad * 8;
    short8 a0 = __builtin_bit_cast(short8, *(const uint4*)&s_sub[w * 32 + l15][kk]);
    short8 a1 = __builtin_bit_cast(short8, *(const uint4*)&s_sub[w * 32 + 16 + l15][kk]);
#pragma unroll
    for (int ct = 0; ct < 4; ++ct) {
      short8 bf = __builtin_bit_cast(
          short8, *(const uint4*)((const char*)s_sigT + sigT_byte(ct * 16 + l15, kk << 1)));
      acc[0][ct] = __builtin_amdgcn_mfma_f32_16x16x32_bf16(a0, bf, acc[0][ct], 0, 0, 0);
      acc[1][ct] = __builtin_amdgcn_mfma_f32_16x16x32_bf16(a1, bf, acc[1][ct], 0, 0, 0);
    }
  }

#pragma unroll
  for (int rt = 0; rt < 2; ++rt) {
    int gr0 = b * 128 + w * 32 + rt * 16 + quad * 4;
#pragma unroll
    for (int ct = 0; ct < 4; ++ct) {
      int col = ct * 16 + l15;
#pragma unroll
      for (int r = 0; r < 4; ++r) {
        z[(size_t)(gr0 + r) * 64 + col] = acc[rt][ct][r];
      }
    }
  }
}

extern "C" void kernel_launch(void* const* d_in, const int* in_sizes, int n_in,
                              void* d_out, int out_size, void* d_ws, size_t ws_size,
                              hipStream_t stream) {
  const float* A  = (const float*)d_in[0];
  const float* mu = (const float*)d_in[1];
  const float* ls = (const float*)d_in[2];
  const float* ep = (const float*)d_in[3];
  const int* nidx = (const int*)d_in[4];

  float* sig = (float*)d_out;                 // 16777216 floats
  float* z   = sig + (size_t)16777216;        // 16777216 floats

  u16* base = (u16*)d_ws;                     // 16 MB of ws + barrier counters
  const size_t MM = (size_t)NG * NG;
  u16* M      = base + 0 * MM;
  u16* MT     = base + 1 * MM;
  u16* P      = base + 2 * MM;
  u16* Msq    = base + 3 * MM;
  u16* MsqT   = base + 4 * MM;
  u16* MsqTI  = base + 5 * MM;
  u16* M4TI   = base + 6 * MM;
  u16* B2     = base + 7 * MM;
  u16* W      = Msq;                          // round 3 writes W into Msq's buffer
  uint32* bar = (uint32*)(base + 8 * MM);     // [0]=arrive, [16]=release

  hipMemsetAsync(bar, 0, 128, stream);        // graph-capturable; defeats ws poisoning
  k_inv<<<256, 512, 0, stream>>>(A, M, MT, P, Msq, MsqT, MsqTI, M4TI, B2, bar);
  k_bmm<<<2048, 256, 0, stream>>>(W, mu, ls, ep, nidx, sig, z);
}

// Round 4
// 388.728 us; speedup vs baseline: 1.1244x; 1.1244x over previous
//
#include <hip/hip_runtime.h>

typedef unsigned int uint32;
typedef unsigned short u16;
typedef __attribute__((ext_vector_type(8))) short short8;
typedef __attribute__((ext_vector_type(4))) float f32x4;

#define NG 1024

__device__ __forceinline__ u16 f2bf(float f) {
  uint32 u = __builtin_bit_cast(uint32, f);
  u += 0x7fffu + ((u >> 16) & 1u);   // round-to-nearest-even
  return (u16)(u >> 16);
}

// async global->LDS DMA, 16B per lane; LDS dest must be wave-uniform base (HW adds lane*16)
__device__ __forceinline__ void glds16(const void* g, void* l) {
  __builtin_amdgcn_global_load_lds((const __attribute__((address_space(1))) void*)g,
                                   (__attribute__((address_space(3))) void*)l,
                                   16, 0, 0);
}

// ---- transpose: M=bf16(A^T), MT=bf16(A), P=bf16(I+A^T). 256 blocks x 256 thr. ----
__global__ __launch_bounds__(256) void k_pre(const float* __restrict__ A,
                                             u16* __restrict__ M,
                                             u16* __restrict__ MT,
                                             u16* __restrict__ P) {
  __shared__ float tile[64][65];
  const int t = threadIdx.x;
  const int bi = blockIdx.x & 15;
  const int bj = blockIdx.x >> 4;
  const int i0 = bi * 64, j0 = bj * 64;
  const int rl = t >> 2;
  const int q = t & 3;
#pragma unroll
  for (int s = 0; s < 4; ++s) {
    int c4 = (q + s * 4) * 4;
    float4 v = *(const float4*)&A[(size_t)(j0 + rl) * NG + i0 + c4];
    tile[rl][c4 + 0] = v.x;
    tile[rl][c4 + 1] = v.y;
    tile[rl][c4 + 2] = v.z;
    tile[rl][c4 + 3] = v.w;
    u16 h0 = f2bf(v.x), h1 = f2bf(v.y), h2 = f2bf(v.z), h3 = f2bf(v.w);
    uint2 pk;
    pk.x = (uint32)h0 | ((uint32)h1 << 16);
    pk.y = (uint32)h2 | ((uint32)h3 << 16);
    *(uint2*)&MT[(size_t)(j0 + rl) * NG + i0 + c4] = pk;   // MT = (A^T)^T = A
  }
  __syncthreads();
#pragma unroll
  for (int s = 0; s < 4; ++s) {
    int c4 = (q + s * 4) * 4;
    int gi = i0 + rl;
    u16 mh[4], ph[4];
#pragma unroll
    for (int u = 0; u < 4; ++u) {
      float f = tile[c4 + u][rl];                 // = M[gi][j0+c4+u]
      mh[u] = f2bf(f);
      float pf = f + ((gi == (j0 + c4 + u)) ? 1.0f : 0.0f);
      ph[u] = f2bf(pf);
    }
    uint2 mk, pkk;
    mk.x = (uint32)mh[0] | ((uint32)mh[1] << 16);
    mk.y = (uint32)mh[2] | ((uint32)mh[3] << 16);
    pkk.x = (uint32)ph[0] | ((uint32)ph[1] << 16);
    pkk.y = (uint32)ph[2] | ((uint32)ph[3] << 16);
    *(uint2*)&M[(size_t)gi * NG + j0 + c4] = mk;
    *(uint2*)&P[(size_t)gi * NG + j0 + c4] = pkk;
  }
}

// ---------------- register-direct 64x64 tile of C = A@B (B passed TRANSPOSED, BT[n][k]).
// No LDS, no barriers: fragments loaded straight from global (L2/L3-resident, 2 MB),
// fully unrolled K so the compiler hoists loads deep; waves slide independently. ----
__device__ __forceinline__ void mm_reg(const u16* __restrict__ A,
                                       const u16* __restrict__ BT,
                                       u16* C, u16* CT, u16* CTI,
                                       int bid) {
  const int t = threadIdx.x;
  const int bm = (bid & 15) * 64;
  const int bn = (bid >> 4) * 64;
  const int wv = t >> 6;
  const int lane = t & 63;
  const int quad = lane >> 4;
  const int l15 = lane & 15;
  const int m0w = (wv >> 1) * 16;   // 4 row-groups x 16 rows
  const int n0w = (wv & 1) * 32;    // 2 col-groups x 32 cols

  // per-lane fragment base pointers; K walks via 64B immediate offsets (0..1984, fits imm13)
  const u16* ap  = A  + (size_t)(bm + m0w + l15) * NG + quad * 8;
  const u16* b0p = BT + (size_t)(bn + n0w + l15) * NG + quad * 8;
  const u16* b1p = BT + (size_t)(bn + n0w + 16 + l15) * NG + quad * 8;

  f32x4 acc[2];
  acc[0] = (f32x4){0.f, 0.f, 0.f, 0.f};
  acc[1] = (f32x4){0.f, 0.f, 0.f, 0.f};

#pragma unroll
  for (int kc = 0; kc < 32; ++kc) {
    short8 af = __builtin_bit_cast(short8, *(const uint4*)(ap + kc * 32));
    short8 b0 = __builtin_bit_cast(short8, *(const uint4*)(b0p + kc * 32));
    short8 b1 = __builtin_bit_cast(short8, *(const uint4*)(b1p + kc * 32));
    acc[0] = __builtin_amdgcn_mfma_f32_16x16x32_bf16(af, b0, acc[0], 0, 0, 0);
    acc[1] = __builtin_amdgcn_mfma_f32_16x16x32_bf16(af, b1, acc[1], 0, 0, 0);
  }

#pragma unroll
  for (int cb = 0; cb < 2; ++cb) {
    int gcol = bn + n0w + cb * 16 + l15;
    int grow = bm + m0w + quad * 4;
    f32x4 v = acc[cb];
    u16 h[4], hI[4];
#pragma unroll
    for (int rr = 0; rr < 4; ++rr) {
      float f = v[rr];
      h[rr] = f2bf(f);
      hI[rr] = f2bf(f + ((gcol == grow + rr) ? 1.0f : 0.0f));
    }
    if (C) {
#pragma unroll
      for (int rr = 0; rr < 4; ++rr) C[(size_t)(grow + rr) * NG + gcol] = h[rr];
    }
    if (CT) {
      uint2 pk;
      pk.x = (uint32)h[0] | ((uint32)h[1] << 16);
      pk.y = (uint32)h[2] | ((uint32)h[3] << 16);
      *(uint2*)&CT[(size_t)gcol * NG + grow] = pk;
    }
    if (CTI) {
      uint2 pk;
      pk.x = (uint32)hI[0] | ((uint32)hI[1] << 16);
      pk.y = (uint32)hI[2] | ((uint32)hI[3] << 16);
      *(uint2*)&CTI[(size_t)gcol * NG + grow] = pk;
    }
  }
}

__global__ __launch_bounds__(512) void k_mm1(const u16* __restrict__ A,
                                             const u16* __restrict__ BT,
                                             u16* __restrict__ C,
                                             u16* __restrict__ CT,
                                             u16* __restrict__ CTI) {
  mm_reg(A, BT, C, CT, CTI, blockIdx.x);
}

// two independent matmuls in one launch
__global__ __launch_bounds__(512) void k_mm_dual(const u16* __restrict__ A0,
                                                 const u16* __restrict__ BT0,
                                                 u16* __restrict__ CTI0,
                                                 const u16* __restrict__ A1,
                                                 const u16* __restrict__ BT1,
                                                 u16* __restrict__ C1) {
  if (blockIdx.x < 256)
    mm_reg(A0, BT0, nullptr, nullptr, CTI0, blockIdx.x);
  else
    mm_reg(A1, BT1, C1, nullptr, nullptr, blockIdx.x - 256);
}

__global__ __launch_bounds__(512) void k_mm3(const u16* __restrict__ A,
                                             const u16* __restrict__ BT,
                                             u16* __restrict__ C) {
  mm_reg(A, BT, C, nullptr, nullptr, blockIdx.x);
}

// sigT: dense [64][128] u16 with chunk-XOR swizzle ((d^(d>>3))&7)<<4 on byte-col.
__device__ __forceinline__ int sigT_byte(int d, int jb) {
  return (d << 8) + (jb ^ (((d ^ (d >> 3)) & 7) << 4));
}

// ---------------- fused: sigma = mu+eps*exp(ls) (+store), gather W[idx,idx], bmm ----
__global__ __launch_bounds__(256) void k_bmm(const u16* __restrict__ W,
                                             const float* __restrict__ mu,
                                             const float* __restrict__ ls,
                                             const float* __restrict__ ep,
                                             const int* __restrict__ nidx,
                                             float* __restrict__ sig,
                                             float* __restrict__ z) {
  __shared__ __align__(16) u16 s_sub[128][136];
  __shared__ __align__(16) u16 s_sigT[8192];
  __shared__ __align__(16) u16 s_row[4][2][1024];   // per-wave double-buffered row
  __shared__ int s_idx[128];

  const int b = blockIdx.x;
  const int t = threadIdx.x;
  const int w = t >> 6;
  const int lane = t & 63;

  if (t < 128) s_idx[t] = nidx[b * 128 + t];

  {  // sigma fused: read mu/ls/ep once, write sig (streaming), stage bf16 sigT
    const size_t off = (size_t)b * 2048;  // float4 units
    const f32x4* mp = (const f32x4*)mu + off;
    const f32x4* lp = (const f32x4*)ls + off;
    const f32x4* epp = (const f32x4*)ep + off;
    f32x4* sp = (f32x4*)sig + off;
#pragma unroll
    for (int q = 0; q < 8; ++q) {
      int f = t + q * 256;
      f32x4 m = __builtin_nontemporal_load(mp + f);
      f32x4 l = __builtin_nontemporal_load(lp + f);
      f32x4 e = __builtin_nontemporal_load(epp + f);
      f32x4 v;
      v.x = m.x + e.x * expf(l.x);
      v.y = m.y + e.y * expf(l.y);
      v.z = m.z + e.z * expf(l.z);
      v.w = m.w + e.w * expf(l.w);
      __builtin_nontemporal_store(v, sp + f);   // sig never re-read (LDS copy feeds MFMA)
      int j = f >> 4;            // k index 0..127
      int d0 = (f & 15) << 2;    // d index 0..63
      *(u16*)((char*)s_sigT + sigT_byte(d0 + 0, j << 1)) = f2bf(v.x);
      *(u16*)((char*)s_sigT + sigT_byte(d0 + 1, j << 1)) = f2bf(v.y);
      *(u16*)((char*)s_sigT + sigT_byte(d0 + 2, j << 1)) = f2bf(v.z);
      *(u16*)((char*)s_sigT + sigT_byte(d0 + 3, j << 1)) = f2bf(v.w);
    }
  }
  __syncthreads();

  {  // W row broadcast via LDS-DMA, then gather columns
    const int gc0 = s_idx[2 * lane];
    const int gc1 = s_idx[2 * lane + 1];
    int r0 = s_idx[w];
    glds16(W + (size_t)r0 * NG + lane * 8, &s_row[w][0][0]);
    glds16(W + (size_t)r0 * NG + 512 + lane * 8, &s_row[w][0][512]);
    for (int it = 0; it < 32; ++it) {
      const int cb = it & 1;
      if (it < 31) {
        int rn = s_idx[w + (it + 1) * 4];
        glds16(W + (size_t)rn * NG + lane * 8, &s_row[w][cb ^ 1][0]);
        glds16(W + (size_t)rn * NG + 512 + lane * 8, &s_row[w][cb ^ 1][512]);
        asm volatile("s_waitcnt vmcnt(2)" ::: "memory");  // current row landed; next in flight
      } else {
        asm volatile("s_waitcnt vmcnt(0)" ::: "memory");
      }
      int i = w + it * 4;
      uint32 lo = s_row[w][cb][gc0];
      uint32 hi = s_row[w][cb][gc1];
      *(uint32*)&s_sub[i][2 * lane] = lo | (hi << 16);  // packed b32, 2-way free
    }
  }
  __syncthreads();

  const int quad = lane >> 4;
  const int l15 = lane & 15;
  f32x4 acc[2][4];
#pragma unroll
  for (int a = 0; a < 2; ++a)
#pragma unroll
    for (int c = 0; c < 4; ++c) acc[a][c] = (f32x4){0.f, 0.f, 0.f, 0.f};

#pragma unroll
  for (int kt = 0; kt < 4; ++kt) {
    int kk = kt * 32 + quad * 8;
    short8 a0 = __builtin_bit_cast(short8, *(const uint4*)&s_sub[w * 32 + l15][kk]);
    short8 a1 = __builtin_bit_cast(short8, *(const uint4*)&s_sub[w * 32 + 16 + l15][kk]);
#pragma unroll
    for (int ct = 0; ct < 4; ++ct) {
      short8 bf = __builtin_bit_cast(
          short8, *(const uint4*)((const char*)s_sigT + sigT_byte(ct * 16 + l15, kk << 1)));
      acc[0][ct] = __builtin_amdgcn_mfma_f32_16x16x32_bf16(a0, bf, acc[0][ct], 0, 0, 0);
      acc[1][ct] = __builtin_amdgcn_mfma_f32_16x16x32_bf16(a1, bf, acc[1][ct], 0, 0, 0);
    }
  }

#pragma unroll
  for (int rt = 0; rt < 2; ++rt) {
    int gr0 = b * 128 + w * 32 + rt * 16 + quad * 4;
#pragma unroll
    for (int ct = 0; ct < 4; ++ct) {
      int col = ct * 16 + l15;
#pragma unroll
      for (int r = 0; r < 4; ++r) {
        z[(size_t)(gr0 + r) * 64 + col] = acc[rt][ct][r];
      }
    }
  }
}

extern "C" void kernel_launch(void* const* d_in, const int* in_sizes, int n_in,
                              void* d_out, int out_size, void* d_ws, size_t ws_size,
                              hipStream_t stream) {
  const float* A  = (const float*)d_in[0];
  const float* mu = (const float*)d_in[1];
  const float* ls = (const float*)d_in[2];
  const float* ep = (const float*)d_in[3];
  const int* nidx = (const int*)d_in[4];

  float* sig = (float*)d_out;                 // 16777216 floats
  float* z   = sig + (size_t)16777216;        // 16777216 floats

  u16* base = (u16*)d_ws;                     // 16 MB of ws
  const size_t MM = (size_t)NG * NG;
  u16* M      = base + 0 * MM;
  u16* MT     = base + 1 * MM;
  u16* P      = base + 2 * MM;
  u16* Msq    = base + 3 * MM;
  u16* MsqT   = base + 4 * MM;
  u16* MsqTI  = base + 5 * MM;
  u16* M4TI   = base + 6 * MM;
  u16* B2     = base + 7 * MM;
  u16* W      = Msq;                          // round 3 writes W into Msq's buffer

  k_pre<<<256, 256, 0, stream>>>(A, M, MT, P);
  // W = (I - A^T)^{-1} ~= (I+M)(I+M^2)(I+M^4), M = A^T  (err ~0.32^8 ~ 1e-4)
  k_mm1<<<256, 512, 0, stream>>>(M, MT, Msq, MsqT, MsqTI);          // M^2, M^2T, I+M^2T
  k_mm_dual<<<512, 512, 0, stream>>>(Msq, MsqT, M4TI,               // (I+M^4)^T
                                     P, MsqTI, B2);                 // B2=(I+M)(I+M^2)
  k_mm3<<<256, 512, 0, stream>>>(B2, M4TI, W);                      // W = B2(I+M^4)
  k_bmm<<<2048, 256, 0, stream>>>(W, mu, ls, ep, nidx, sig, z);
}

// Round 5
// 363.638 us; speedup vs baseline: 1.2020x; 1.0690x over previous
//
#include <hip/hip_runtime.h>

typedef unsigned int uint32;
typedef unsigned short u16;
typedef __attribute__((ext_vector_type(8))) short short8;
typedef __attribute__((ext_vector_type(4))) float f32x4;

#define NG 1024

__device__ __forceinline__ u16 f2bf(float f) {
  uint32 u = __builtin_bit_cast(uint32, f);
  u += 0x7fffu + ((u >> 16) & 1u);   // round-to-nearest-even
  return (u16)(u >> 16);
}

// async global->LDS DMA, 16B per lane; LDS dest must be wave-uniform base (HW adds lane*16)
__device__ __forceinline__ void glds16(const void* g, void* l) {
  __builtin_amdgcn_global_load_lds((const __attribute__((address_space(1))) void*)g,
                                   (__attribute__((address_space(3))) void*)l,
                                   16, 0, 0);
}

// ---- single-use grid barrier slot: arrive, spin until all 256 blocks arrived.
// No generation/reset logic (each sync point has its own counter, zeroed by k_pre).
// 256 blocks x 1/CU guaranteed co-resident. AGENT-scope atomics + threadfence
// give cross-XCD release/acquire. ----
__device__ __forceinline__ void gbar1(uint32* slot, uint32 nb) {
  __syncthreads();
  if (threadIdx.x == 0) {
    __threadfence();   // release this block's global writes
    __hip_atomic_fetch_add(slot, 1u, __ATOMIC_ACQ_REL, __HIP_MEMORY_SCOPE_AGENT);
    while (__hip_atomic_load(slot, __ATOMIC_ACQUIRE, __HIP_MEMORY_SCOPE_AGENT) < nb) {
      __builtin_amdgcn_s_sleep(1);
    }
    __threadfence();   // acquire peers' writes before reading them
  }
  __syncthreads();
}

// ---- transpose: M=bf16(A^T), MT=bf16(A), P=bf16(I+A^T); also zeroes barrier slots ----
__global__ __launch_bounds__(256) void k_pre(const float* __restrict__ A,
                                             u16* __restrict__ M,
                                             u16* __restrict__ MT,
                                             u16* __restrict__ P,
                                             uint32* __restrict__ bar) {
  __shared__ float tile[64][65];
  const int t = threadIdx.x;
  if (blockIdx.x == 0 && t < 32) bar[t] = 0;   // zero both slots (128 B), graph-clean
  const int bi = blockIdx.x & 15;
  const int bj = blockIdx.x >> 4;
  const int i0 = bi * 64, j0 = bj * 64;
  const int rl = t >> 2;
  const int q = t & 3;
#pragma unroll
  for (int s = 0; s < 4; ++s) {
    int c4 = (q + s * 4) * 4;
    float4 v = *(const float4*)&A[(size_t)(j0 + rl) * NG + i0 + c4];
    tile[rl][c4 + 0] = v.x;
    tile[rl][c4 + 1] = v.y;
    tile[rl][c4 + 2] = v.z;
    tile[rl][c4 + 3] = v.w;
    u16 h0 = f2bf(v.x), h1 = f2bf(v.y), h2 = f2bf(v.z), h3 = f2bf(v.w);
    uint2 pk;
    pk.x = (uint32)h0 | ((uint32)h1 << 16);
    pk.y = (uint32)h2 | ((uint32)h3 << 16);
    *(uint2*)&MT[(size_t)(j0 + rl) * NG + i0 + c4] = pk;   // MT = (A^T)^T = A
  }
  __syncthreads();
#pragma unroll
  for (int s = 0; s < 4; ++s) {
    int c4 = (q + s * 4) * 4;
    int gi = i0 + rl;
    u16 mh[4], ph[4];
#pragma unroll
    for (int u = 0; u < 4; ++u) {
      float f = tile[c4 + u][rl];                 // = M[gi][j0+c4+u]
      mh[u] = f2bf(f);
      float pf = f + ((gi == (j0 + c4 + u)) ? 1.0f : 0.0f);
      ph[u] = f2bf(pf);
    }
    uint2 mk, pkk;
    mk.x = (uint32)mh[0] | ((uint32)mh[1] << 16);
    mk.y = (uint32)mh[2] | ((uint32)mh[3] << 16);
    pkk.x = (uint32)ph[0] | ((uint32)ph[1] << 16);
    pkk.y = (uint32)ph[2] | ((uint32)ph[3] << 16);
    *(uint2*)&M[(size_t)gi * NG + j0 + c4] = mk;
    *(uint2*)&P[(size_t)gi * NG + j0 + c4] = pkk;
  }
}

// swizzled LDS tile read: linear [64][128B] tile, chunk-XOR ((r&7)<<4)
__device__ __forceinline__ short8 ldfrag(const u16* tile, int r, int kkB) {
  const char* p = (const char*)tile + r * 128 + (kkB ^ ((r & 7) << 4));
  return __builtin_bit_cast(short8, *(const uint4*)p);
}

// ---------------- one 64x64 output tile of C = A@B (B passed TRANSPOSED as BT[n][k]).
// depth-2 global_load_lds pipeline (3-buffer ring), counted vmcnt, raw barriers.
// (verbatim r2 body — proven ~20-23 us/round inside the fused chain) ----
__device__ __forceinline__ void mm_tile(const u16* __restrict__ A,
                                        const u16* __restrict__ BT,
                                        u16* C, u16* CT, u16* CTI,
                                        int bid, u16* sA, u16* sB) {
  const int t = threadIdx.x;
  const int bm = (bid & 15) * 64;
  const int bn = (bid >> 4) * 64;
  const int wv = t >> 6;
  const int lane = t & 63;
  const int quad = lane >> 4;
  const int l15 = lane & 15;
  const int m0w = (wv & 3) * 16;   // 16-row strip per wave
  const int n0w = (wv >> 2) * 32;  // 32-col strip per wave

  // staging: LDS linear (slot t*16B); global source col inverse-swizzled (rule 21)
  const int srow = t >> 3;                 // 0..63
  const int scolb = (t & 7) << 4;          // byte col 0..112
  const int scol = (scolb ^ ((srow & 7) << 4)) >> 1;  // elem col
  const u16* aS = A + (size_t)(bm + srow) * NG + scol;
  const u16* bS = BT + (size_t)(bn + srow) * NG + scol;
  const int ldoff = wv << 9;   // per-wave 1KB slice within a buffer

  f32x4 acc[2];
  acc[0] = (f32x4){0.f, 0.f, 0.f, 0.f};
  acc[1] = (f32x4){0.f, 0.f, 0.f, 0.f};

  // prologue: stage kb=0 and kb=1
  glds16(aS, sA + ldoff);
  glds16(bS, sB + ldoff);
  glds16(aS + 64, sA + 4096 + ldoff);
  glds16(bS + 64, sB + 4096 + ldoff);

#pragma unroll
  for (int kb = 0; kb < 16; ++kb) {
    if (kb < 14) {
      const int nb = (kb + 2) % 3;
      glds16(aS + (kb + 2) * 64, sA + nb * 4096 + ldoff);
      glds16(bS + (kb + 2) * 64, sB + nb * 4096 + ldoff);
      asm volatile("s_waitcnt vmcnt(4)" ::: "memory");  // kb landed; kb+1,kb+2 in flight
    } else if (kb == 14) {
      asm volatile("s_waitcnt vmcnt(2)" ::: "memory");
    } else {
      asm volatile("s_waitcnt vmcnt(0)" ::: "memory");
    }
    __builtin_amdgcn_s_barrier();
    __builtin_amdgcn_sched_barrier(0);
    const u16* At = sA + (kb % 3) * 4096;
    const u16* Bt = sB + (kb % 3) * 4096;
#pragma unroll
    for (int ks = 0; ks < 2; ++ks) {
      int kkB = ks * 64 + quad * 16;
      short8 af = ldfrag(At, m0w + l15, kkB);
      short8 b0 = ldfrag(Bt, n0w + l15, kkB);
      short8 b1 = ldfrag(Bt, n0w + 16 + l15, kkB);
      acc[0] = __builtin_amdgcn_mfma_f32_16x16x32_bf16(af, b0, acc[0], 0, 0, 0);
      acc[1] = __builtin_amdgcn_mfma_f32_16x16x32_bf16(af, b1, acc[1], 0, 0, 0);
    }
    __builtin_amdgcn_sched_barrier(0);
    __builtin_amdgcn_s_barrier();   // protect ring buffer about to be re-staged
  }

#pragma unroll
  for (int cb = 0; cb < 2; ++cb) {
    int gcol = bn + n0w + cb * 16 + l15;
    int grow = bm + m0w + quad * 4;
    f32x4 v = acc[cb];
    u16 h[4], hI[4];
#pragma unroll
    for (int rr = 0; rr < 4; ++rr) {
      float f = v[rr];
      h[rr] = f2bf(f);
      hI[rr] = f2bf(f + ((gcol == grow + rr) ? 1.0f : 0.0f));
    }
    if (C) {
#pragma unroll
      for (int rr = 0; rr < 4; ++rr) C[(size_t)(grow + rr) * NG + gcol] = h[rr];
    }
    if (CT) {
      uint2 pk;
      pk.x = (uint32)h[0] | ((uint32)h[1] << 16);
      pk.y = (uint32)h[2] | ((uint32)h[3] << 16);
      *(uint2*)&CT[(size_t)gcol * NG + grow] = pk;
    }
    if (CTI) {
      uint2 pk;
      pk.x = (uint32)hI[0] | ((uint32)hI[1] << 16);
      pk.y = (uint32)hI[2] | ((uint32)hI[3] << 16);
      *(uint2*)&CTI[(size_t)gcol * NG + grow] = pk;
    }
  }
}

// ---------------- fused mm chain (3 rounds, 2 single-use grid barriers).
// W = (I - A^T)^{-1} ~= (I+M)(I+M^2)(I+M^4); round 3 writes W into Msq's buffer. ----
__global__ __launch_bounds__(512) void k_inv(const u16* __restrict__ M,
                                             const u16* __restrict__ MT,
                                             const u16* __restrict__ P,
                                             u16* __restrict__ Msq,   // also W output
                                             u16* __restrict__ MsqT,
                                             u16* __restrict__ MsqTI,
                                             u16* __restrict__ M4TI,
                                             u16* __restrict__ B2,
                                             uint32* __restrict__ bar) {
  __shared__ __align__(16) u16 smem[24576];   // 48 KB: sA 3x8KB | sB 3x8KB
  u16* sA = smem;
  u16* sB = smem + 12288;
  const int bid = blockIdx.x;

  // round 1: Msq = M*M, MsqT = Msq^T, MsqTI = I + Msq^T  (M/MT/P from k_pre via launch order)
  mm_tile(M, MT, Msq, MsqT, MsqTI, bid, sA, sB);
  gbar1(bar + 0, 256);
  // round 2 (two independent tiles per block): M4TI = (I+M^4)^T ; B2 = (I+M)(I+M^2)
  mm_tile(Msq, MsqT, nullptr, nullptr, M4TI, bid, sA, sB);
  mm_tile(P, MsqTI, B2, nullptr, nullptr, bid, sA, sB);
  gbar1(bar + 16, 256);
  // round 3: W = B2 * (I+M^4)   (written into Msq's buffer; all round-2 reads of Msq done)
  mm_tile(B2, M4TI, Msq, nullptr, nullptr, bid, sA, sB);
}

// sigT: dense [64][128] u16 with chunk-XOR swizzle ((d^(d>>3))&7)<<4 on byte-col.
__device__ __forceinline__ int sigT_byte(int d, int jb) {
  return (d << 8) + (jb ^ (((d ^ (d >> 3)) & 7) << 4));
}

// ---------------- fused: sigma = mu+eps*exp(ls) (+store), gather W[idx,idx], bmm ----
__global__ __launch_bounds__(256) void k_bmm(const u16* __restrict__ W,
                                             const float* __restrict__ mu,
                                             const float* __restrict__ ls,
                                             const float* __restrict__ ep,
                                             const int* __restrict__ nidx,
                                             float* __restrict__ sig,
                                             float* __restrict__ z) {
  __shared__ __align__(16) u16 s_sub[128][136];
  __shared__ __align__(16) u16 s_sigT[8192];
  __shared__ __align__(16) u16 s_row[4][2][1024];   // per-wave double-buffered row
  __shared__ int s_idx[128];

  const int b = blockIdx.x;
  const int t = threadIdx.x;
  const int w = t >> 6;
  const int lane = t & 63;

  if (t < 128) s_idx[t] = nidx[b * 128 + t];

  {  // sigma fused: read mu/ls/ep once, write sig (streaming), stage bf16 sigT
    const size_t off = (size_t)b * 2048;  // float4 units
    const f32x4* mp = (const f32x4*)mu + off;
    const f32x4* lp = (const f32x4*)ls + off;
    const f32x4* epp = (const f32x4*)ep + off;
    f32x4* sp = (f32x4*)sig + off;
#pragma unroll
    for (int q = 0; q < 8; ++q) {
      int f = t + q * 256;
      f32x4 m = __builtin_nontemporal_load(mp + f);
      f32x4 l = __builtin_nontemporal_load(lp + f);
      f32x4 e = __builtin_nontemporal_load(epp + f);
      f32x4 v;
      v.x = m.x + e.x * expf(l.x);
      v.y = m.y + e.y * expf(l.y);
      v.z = m.z + e.z * expf(l.z);
      v.w = m.w + e.w * expf(l.w);
      __builtin_nontemporal_store(v, sp + f);   // sig never re-read (LDS copy feeds MFMA)
      int j = f >> 4;            // k index 0..127
      int d0 = (f & 15) << 2;    // d index 0..63
      *(u16*)((char*)s_sigT + sigT_byte(d0 + 0, j << 1)) = f2bf(v.x);
      *(u16*)((char*)s_sigT + sigT_byte(d0 + 1, j << 1)) = f2bf(v.y);
      *(u16*)((char*)s_sigT + sigT_byte(d0 + 2, j << 1)) = f2bf(v.z);
      *(u16*)((char*)s_sigT + sigT_byte(d0 + 3, j << 1)) = f2bf(v.w);
    }
  }
  __syncthreads();

  {  // W row broadcast via LDS-DMA, then gather columns
    const int gc0 = s_idx[2 * lane];
    const int gc1 = s_idx[2 * lane + 1];
    int r0 = s_idx[w];
    glds16(W + (size_t)r0 * NG + lane * 8, &s_row[w][0][0]);
    glds16(W + (size_t)r0 * NG + 512 + lane * 8, &s_row[w][0][512]);
    for (int it = 0; it < 32; ++it) {
      const int cb = it & 1;
      if (it < 31) {
        int rn = s_idx[w + (it + 1) * 4];
        glds16(W + (size_t)rn * NG + lane * 8, &s_row[w][cb ^ 1][0]);
        glds16(W + (size_t)rn * NG + 512 + lane * 8, &s_row[w][cb ^ 1][512]);
        asm volatile("s_waitcnt vmcnt(2)" ::: "memory");  // current row landed; next in flight
      } else {
        asm volatile("s_waitcnt vmcnt(0)" ::: "memory");
      }
      int i = w + it * 4;
      uint32 lo = s_row[w][cb][gc0];
      uint32 hi = s_row[w][cb][gc1];
      *(uint32*)&s_sub[i][2 * lane] = lo | (hi << 16);  // packed b32, 2-way free
    }
  }
  __syncthreads();

  const int quad = lane >> 4;
  const int l15 = lane & 15;
  f32x4 acc[2][4];
#pragma unroll
  for (int a = 0; a < 2; ++a)
#pragma unroll
    for (int c = 0; c < 4; ++c) acc[a][c] = (f32x4){0.f, 0.f, 0.f, 0.f};

#pragma unroll
  for (int kt = 0; kt < 4; ++kt) {
    int kk = kt * 32 + quad * 8;
    short8 a0 = __builtin_bit_cast(short8, *(const uint4*)&s_sub[w * 32 + l15][kk]);
    short8 a1 = __builtin_bit_cast(short8, *(const uint4*)&s_sub[w * 32 + 16 + l15][kk]);
#pragma unroll
    for (int ct = 0; ct < 4; ++ct) {
      short8 bf = __builtin_bit_cast(
          short8, *(const uint4*)((const char*)s_sigT + sigT_byte(ct * 16 + l15, kk << 1)));
      acc[0][ct] = __builtin_amdgcn_mfma_f32_16x16x32_bf16(a0, bf, acc[0][ct], 0, 0, 0);
      acc[1][ct] = __builtin_amdgcn_mfma_f32_16x16x32_bf16(a1, bf, acc[1][ct], 0, 0, 0);
    }
  }

#pragma unroll
  for (int rt = 0; rt < 2; ++rt) {
    int gr0 = b * 128 + w * 32 + rt * 16 + quad * 4;
#pragma unroll
    for (int ct = 0; ct < 4; ++ct) {
      int col = ct * 16 + l15;
#pragma unroll
      for (int r = 0; r < 4; ++r) {
        z[(size_t)(gr0 + r) * 64 + col] = acc[rt][ct][r];
      }
    }
  }
}

extern "C" void kernel_launch(void* const* d_in, const int* in_sizes, int n_in,
                              void* d_out, int out_size, void* d_ws, size_t ws_size,
                              hipStream_t stream) {
  const float* A  = (const float*)d_in[0];
  const float* mu = (const float*)d_in[1];
  const float* ls = (const float*)d_in[2];
  const float* ep = (const float*)d_in[3];
  const int* nidx = (const int*)d_in[4];

  float* sig = (float*)d_out;                 // 16777216 floats
  float* z   = sig + (size_t)16777216;        // 16777216 floats

  u16* base = (u16*)d_ws;                     // 16 MB of ws + barrier counters
  const size_t MM = (size_t)NG * NG;
  u16* M      = base + 0 * MM;
  u16* MT     = base + 1 * MM;
  u16* P      = base + 2 * MM;
  u16* Msq    = base + 3 * MM;
  u16* MsqT   = base + 4 * MM;
  u16* MsqTI  = base + 5 * MM;
  u16* M4TI   = base + 6 * MM;
  u16* B2     = base + 7 * MM;
  u16* W      = Msq;                          // round 3 writes W into Msq's buffer
  uint32* bar = (uint32*)(base + 8 * MM);     // slots: [0], [16] (zeroed by k_pre)

  k_pre<<<256, 256, 0, stream>>>(A, M, MT, P, bar);
  k_inv<<<256, 512, 0, stream>>>(M, MT, P, Msq, MsqT, MsqTI, M4TI, B2, bar);
  k_bmm<<<2048, 256, 0, stream>>>(W, mu, ls, ep, nidx, sig, z);
}